// Round 2
// baseline (607.441 us; speedup 1.0000x reference)
//
#include <hip/hip_runtime.h>
#include <math.h>

#define FIN 128
#define HID 16
#define NC 8

// ---------------------------------------------------------------------------
// dtype probe: int64 vs int32 edge_index (device-side, uniform branch later)
// ---------------------------------------------------------------------------
__global__ void detect64_kernel(const void* __restrict__ ei, int E, int N,
                                int* __restrict__ flag) {
    if (blockIdx.x == 0 && threadIdx.x == 0) {
        const long long* p = (const long long*)ei;
        int ok = 1;
        for (int i = 0; i < 16; ++i) {
            long long v = p[i];
            if (v < 0 || v >= (long long)N) { ok = 0; break; }
        }
        *flag = ok;
    }
}

__device__ __forceinline__ int edge_at(const void* __restrict__ ei, long long pos, int is64) {
    return is64 ? (int)((const long long*)ei)[pos] : ((const int*)ei)[pos];
}

// counts[dst[e]]++  (int atomics)
__global__ void hist_kernel(const void* __restrict__ ei, int E,
                            const int* __restrict__ flag, int* __restrict__ counts) {
    int is64 = *flag;
    for (int e = blockIdx.x * blockDim.x + threadIdx.x; e < E;
         e += gridDim.x * blockDim.x) {
        int d = edge_at(ei, (long long)E + e, is64);
        atomicAdd(&counts[d], 1);
    }
}

// exclusive scan, stage A: 1024 elements/block (256 thr x 4), block totals out
__global__ void scanA_kernel(const int* __restrict__ counts, int* __restrict__ off,
                             int* __restrict__ bsum, int N) {
    __shared__ int s[256];
    int b = blockIdx.x, t = threadIdx.x;
    int base = b * 1024 + t * 4;
    int v[4], tot = 0;
#pragma unroll
    for (int i = 0; i < 4; ++i) {
        int idx = base + i;
        v[i] = (idx < N) ? counts[idx] : 0;
        tot += v[i];
    }
    s[t] = tot;
    __syncthreads();
    for (int d = 1; d < 256; d <<= 1) {
        int add = (t >= d) ? s[t - d] : 0;
        __syncthreads();
        s[t] += add;
        __syncthreads();
    }
    if (t == 255) bsum[b] = s[255];
    int run = (t > 0) ? s[t - 1] : 0;
#pragma unroll
    for (int i = 0; i < 4; ++i) {
        int idx = base + i;
        if (idx < N) off[idx] = run;
        run += v[i];
    }
}

// stage B: scan the ~98 block sums (trivial serial)
__global__ void scanB_kernel(int* __restrict__ bsum, int nb) {
    if (threadIdx.x == 0 && blockIdx.x == 0) {
        int run = 0;
        for (int i = 0; i < nb; ++i) { int v = bsum[i]; bsum[i] = run; run += v; }
    }
}

// stage C: add block offsets
__global__ void scanC_kernel(int* __restrict__ off, const int* __restrict__ bsum, int N) {
    int i = blockIdx.x * blockDim.x + threadIdx.x;
    if (i < N) off[i] += bsum[i >> 10];
}

// dinv[n] = rsqrt(counts[n] + 1)   (self loop adds 1)
__global__ void dinv_kernel(const int* __restrict__ counts, float* __restrict__ dinv, int N) {
    int n = blockIdx.x * blockDim.x + threadIdx.x;
    if (n < N) dinv[n] = rsqrtf((float)(counts[n] + 1));
}

// csr_src[slot] = src; off[d] advances to its end pointer (no cursor array)
__global__ void scatter_kernel(const void* __restrict__ ei, int E,
                               const int* __restrict__ flag,
                               int* __restrict__ off, int* __restrict__ csr_src) {
    int is64 = *flag;
    for (int e = blockIdx.x * blockDim.x + threadIdx.x; e < E;
         e += gridDim.x * blockDim.x) {
        int s = edge_at(ei, e, is64);
        int d = edge_at(ei, (long long)E + e, is64);
        int pos = atomicAdd(&off[d], 1);
        csr_src[pos] = s;
    }
}

// g1[n][k] = (sum_f x[n][f] * W1[f][k]) * dinv[n]
__global__ void transform1_kernel(const float* __restrict__ x,
                                  const float* __restrict__ W1,
                                  const float* __restrict__ dinv,
                                  float* __restrict__ g1, int N) {
    __shared__ float xs[16][FIN + 4];
    __shared__ float w[FIN][HID];
    const int t = threadIdx.x;
    for (int i = t; i < FIN * HID; i += 256) w[i / HID][i % HID] = W1[i];

    const float4* x4 = (const float4*)x;
    for (int rb = blockIdx.x * 16; rb < N; rb += gridDim.x * 16) {
        __syncthreads();
        for (int i = t; i < 16 * FIN / 4; i += 256) {
            int r = i >> 5, f4 = i & 31;
            int row = rb + r;
            float4 v = (row < N) ? x4[(size_t)row * (FIN / 4) + f4]
                                 : make_float4(0.f, 0.f, 0.f, 0.f);
            *((float4*)&xs[r][f4 * 4]) = v;
        }
        __syncthreads();
        int r = t >> 4, k = t & 15;
        int row = rb + r;
        if (row < N) {
            float s = 0.f;
#pragma unroll
            for (int f = 0; f < FIN; ++f) s += xs[r][f] * w[f][k];
            g1[(size_t)row * HID + k] = s * dinv[row];
        }
    }
}

// wave per node: 16 feature lanes x 4 edge-ways; fused ReLU finalize
__global__ void agg1_kernel(const int* __restrict__ off, const int* __restrict__ csr_src,
                            const float* __restrict__ g1, const float* __restrict__ dinv,
                            const float* __restrict__ b1, float* __restrict__ h, int N) {
    int wid = threadIdx.x >> 6;
    int lane = threadIdx.x & 63;
    int k = lane & 15, j = lane >> 4;                 // j in 0..3
    int wavesTotal = gridDim.x * (blockDim.x >> 6);
    for (int n = blockIdx.x * (blockDim.x >> 6) + wid; n < N; n += wavesTotal) {
        int start = (n == 0) ? 0 : off[n - 1];        // off[] holds END after scatter
        int end = off[n];
        float sum = 0.f;
        for (int e = start + j; e < end; e += 4)
            sum += g1[(size_t)csr_src[e] * HID + k];
        sum += __shfl_xor(sum, 16, 64);
        sum += __shfl_xor(sum, 32, 64);
        if (lane < 16) {
            float v = dinv[n] * (sum + g1[(size_t)n * HID + k]) + b1[k];
            h[(size_t)n * HID + k] = fmaxf(v, 0.f);
        }
    }
}

// g2[n][c] = (sum_k h[n][k] * W2[k][c]) * dinv[n]
__global__ void transform2_kernel(const float* __restrict__ h,
                                  const float* __restrict__ W2,
                                  const float* __restrict__ dinv,
                                  float* __restrict__ g2, int N) {
    int total = N * NC;
    for (int idx = blockIdx.x * blockDim.x + threadIdx.x; idx < total;
         idx += gridDim.x * blockDim.x) {
        int n = idx >> 3, c = idx & 7;
        float s = 0.f;
#pragma unroll
        for (int k = 0; k < HID; ++k) s += h[n * HID + k] * W2[k * NC + c];
        g2[idx] = s * dinv[n];
    }
}

// wave per node: 8 feature lanes x 8 edge-ways; fused log_softmax
__global__ void agg2_kernel(const int* __restrict__ off, const int* __restrict__ csr_src,
                            const float* __restrict__ g2, const float* __restrict__ dinv,
                            const float* __restrict__ b2, float* __restrict__ out, int N) {
    int wid = threadIdx.x >> 6;
    int lane = threadIdx.x & 63;
    int k = lane & 7, j = lane >> 3;                  // j in 0..7
    int wavesTotal = gridDim.x * (blockDim.x >> 6);
    for (int n = blockIdx.x * (blockDim.x >> 6) + wid; n < N; n += wavesTotal) {
        int start = (n == 0) ? 0 : off[n - 1];
        int end = off[n];
        float sum = 0.f;
        for (int e = start + j; e < end; e += 8)
            sum += g2[(size_t)csr_src[e] * NC + k];
        sum += __shfl_xor(sum, 8, 64);
        sum += __shfl_xor(sum, 16, 64);
        sum += __shfl_xor(sum, 32, 64);
        float logit = dinv[n] * (sum + g2[(size_t)n * NC + k]) + b2[k];
        float m = logit;
        m = fmaxf(m, __shfl_xor(m, 1, 64));
        m = fmaxf(m, __shfl_xor(m, 2, 64));
        m = fmaxf(m, __shfl_xor(m, 4, 64));
        float ex = __expf(logit - m);
        float s = ex;
        s += __shfl_xor(s, 1, 64);
        s += __shfl_xor(s, 2, 64);
        s += __shfl_xor(s, 4, 64);
        float lse = m + __logf(s);
        if (lane < 8) out[(size_t)n * NC + k] = logit - lse;
    }
}

extern "C" void kernel_launch(void* const* d_in, const int* in_sizes, int n_in,
                              void* d_out, int out_size, void* d_ws, size_t ws_size,
                              hipStream_t stream) {
    const float* x  = (const float*)d_in[0];
    const void*  ei = d_in[1];
    const float* W1 = (const float*)d_in[2];
    const float* b1 = (const float*)d_in[3];
    const float* W2 = (const float*)d_in[4];
    const float* b2 = (const float*)d_in[5];

    const int N = in_sizes[0] / FIN;
    const int E = in_sizes[1] / 2;
    const int NB = (N + 1023) / 1024;

    char* p = (char*)d_ws;
    int*   counts  = (int*)p;            p += (size_t)N * 4;
    int*   off     = (int*)p;            p += (size_t)N * 4;
    int*   bsum    = (int*)p;            p += (size_t)((NB + 63) & ~63) * 4;
    int*   csr_src = (int*)p;            p += (size_t)E * 4;
    float* dinv    = (float*)p;          p += (size_t)N * 4;
    float* g1      = (float*)p;          p += (size_t)N * HID * 4;
    float* h       = (float*)p;          p += (size_t)N * HID * 4;
    float* g2      = (float*)p;          p += (size_t)N * NC * 4;
    int*   flag    = (int*)p;

    hipMemsetAsync(counts, 0, (size_t)N * sizeof(int), stream);

    detect64_kernel<<<1, 64, 0, stream>>>(ei, E, N, flag);
    hist_kernel<<<2048, 256, 0, stream>>>(ei, E, flag, counts);
    scanA_kernel<<<NB, 256, 0, stream>>>(counts, off, bsum, N);
    scanB_kernel<<<1, 64, 0, stream>>>(bsum, NB);
    scanC_kernel<<<(N + 255) / 256, 256, 0, stream>>>(off, bsum, N);
    dinv_kernel<<<(N + 255) / 256, 256, 0, stream>>>(counts, dinv, N);
    scatter_kernel<<<2048, 256, 0, stream>>>(ei, E, flag, off, csr_src);

    transform1_kernel<<<(N + 15) / 16, 256, 0, stream>>>(x, W1, dinv, g1, N);
    agg1_kernel<<<8192, 256, 0, stream>>>(off, csr_src, g1, dinv, b1, h, N);
    transform2_kernel<<<2048, 256, 0, stream>>>(h, W2, dinv, g2, N);
    agg2_kernel<<<8192, 256, 0, stream>>>(off, csr_src, g2, dinv, b2,
                                          (float*)d_out, N);
}

// Round 3
// 457.832 us; speedup vs baseline: 1.3268x; 1.3268x over previous
//
#include <hip/hip_runtime.h>
#include <math.h>

#define FIN 128
#define HID 16
#define NC 8
#define NPART 8

// ---------------------------------------------------------------------------
// dtype probe: int64 vs int32 edge_index (device-side, uniform branch later)
// ---------------------------------------------------------------------------
__global__ void detect64_kernel(const void* __restrict__ ei, int E, int N,
                                int* __restrict__ flag) {
    if (blockIdx.x == 0 && threadIdx.x == 0) {
        const long long* p = (const long long*)ei;
        int ok = 1;
        for (int i = 0; i < 16; ++i) {
            long long v = p[i];
            if (v < 0 || v >= (long long)N) { ok = 0; break; }
        }
        *flag = ok;
    }
}

__device__ __forceinline__ int edge_at(const void* __restrict__ ei, long long pos, int is64) {
    return is64 ? (int)((const long long*)ei)[pos] : ((const int*)ei)[pos];
}

// XCD-pinned histogram: block b handles partition b%8 (round-robin XCD map);
// counts[] slice for that partition stays in one XCD's L2.
__global__ void hist_part_kernel(const void* __restrict__ ei, int E, int N,
                                 const int* __restrict__ flag, int* __restrict__ counts) {
    const int is64 = *flag;
    const int part = blockIdx.x & (NPART - 1);
    const int PS = (N + NPART - 1) / NPART;
    const int lo = part * PS;
    const int hi = (lo + PS < N) ? lo + PS : N;
    const int gstride = (gridDim.x >> 3) * blockDim.x;
    for (int e = (blockIdx.x >> 3) * blockDim.x + threadIdx.x; e < E; e += gstride) {
        int d = edge_at(ei, (long long)E + e, is64);
        if (d >= lo && d < hi) atomicAdd(&counts[d], 1);
    }
}

// exclusive scan, stage A: 1024 elements/block (256 thr x 4), block totals out
__global__ void scanA_kernel(const int* __restrict__ counts, int* __restrict__ off,
                             int* __restrict__ bsum, int N) {
    __shared__ int s[256];
    int b = blockIdx.x, t = threadIdx.x;
    int base = b * 1024 + t * 4;
    int v[4], tot = 0;
#pragma unroll
    for (int i = 0; i < 4; ++i) {
        int idx = base + i;
        v[i] = (idx < N) ? counts[idx] : 0;
        tot += v[i];
    }
    s[t] = tot;
    __syncthreads();
    for (int d = 1; d < 256; d <<= 1) {
        int add = (t >= d) ? s[t - d] : 0;
        __syncthreads();
        s[t] += add;
        __syncthreads();
    }
    if (t == 255) bsum[b] = s[255];
    int run = (t > 0) ? s[t - 1] : 0;
#pragma unroll
    for (int i = 0; i < 4; ++i) {
        int idx = base + i;
        if (idx < N) off[idx] = run;
        run += v[i];
    }
}

// stage B: scan the ~98 block sums (trivial serial)
__global__ void scanB_kernel(int* __restrict__ bsum, int nb) {
    if (threadIdx.x == 0 && blockIdx.x == 0) {
        int run = 0;
        for (int i = 0; i < nb; ++i) { int v = bsum[i]; bsum[i] = run; run += v; }
    }
}

// stage C: add block offsets
__global__ void scanC_kernel(int* __restrict__ off, const int* __restrict__ bsum, int N) {
    int i = blockIdx.x * blockDim.x + threadIdx.x;
    if (i < N) off[i] += bsum[i >> 10];
}

// dinv[n] = rsqrt(counts[n] + 1)   (self loop adds 1)
__global__ void dinv_kernel(const int* __restrict__ counts, float* __restrict__ dinv, int N) {
    int n = blockIdx.x * blockDim.x + threadIdx.x;
    if (n < N) dinv[n] = rsqrtf((float)(counts[n] + 1));
}

// XCD-pinned scatter: partition p's off[] slice (50KB) and csr_src slice
// (~1.6MB) are written only from XCD p -> lines stay in local L2, evict once.
// off[d] advances to its end pointer (no cursor array).
__global__ void scatter_part_kernel(const void* __restrict__ ei, int E, int N,
                                    const int* __restrict__ flag,
                                    int* __restrict__ off, int* __restrict__ csr_src) {
    const int is64 = *flag;
    const int part = blockIdx.x & (NPART - 1);
    const int PS = (N + NPART - 1) / NPART;
    const int lo = part * PS;
    const int hi = (lo + PS < N) ? lo + PS : N;
    const int gstride = (gridDim.x >> 3) * blockDim.x;
    for (int e = (blockIdx.x >> 3) * blockDim.x + threadIdx.x; e < E; e += gstride) {
        int d = edge_at(ei, (long long)E + e, is64);
        if (d >= lo && d < hi) {
            int s = edge_at(ei, e, is64);
            int pos = atomicAdd(&off[d], 1);
            csr_src[pos] = s;
        }
    }
}

// g1[n][k] = (sum_f x[n][f] * W1[f][k]) * dinv[n]
__global__ void transform1_kernel(const float* __restrict__ x,
                                  const float* __restrict__ W1,
                                  const float* __restrict__ dinv,
                                  float* __restrict__ g1, int N) {
    __shared__ float xs[16][FIN + 4];
    __shared__ float w[FIN][HID];
    const int t = threadIdx.x;
    for (int i = t; i < FIN * HID; i += 256) w[i / HID][i % HID] = W1[i];

    const float4* x4 = (const float4*)x;
    for (int rb = blockIdx.x * 16; rb < N; rb += gridDim.x * 16) {
        __syncthreads();
        for (int i = t; i < 16 * FIN / 4; i += 256) {
            int r = i >> 5, f4 = i & 31;
            int row = rb + r;
            float4 v = (row < N) ? x4[(size_t)row * (FIN / 4) + f4]
                                 : make_float4(0.f, 0.f, 0.f, 0.f);
            *((float4*)&xs[r][f4 * 4]) = v;
        }
        __syncthreads();
        int r = t >> 4, k = t & 15;
        int row = rb + r;
        if (row < N) {
            float s = 0.f;
#pragma unroll
            for (int f = 0; f < FIN; ++f) s += xs[r][f] * w[f][k];
            g1[(size_t)row * HID + k] = s * dinv[row];
        }
    }
}

// wave per node: 16 feature lanes x 4 edge-ways; fused ReLU finalize
__global__ void agg1_kernel(const int* __restrict__ off, const int* __restrict__ csr_src,
                            const float* __restrict__ g1, const float* __restrict__ dinv,
                            const float* __restrict__ b1, float* __restrict__ h, int N) {
    int wid = threadIdx.x >> 6;
    int lane = threadIdx.x & 63;
    int k = lane & 15, j = lane >> 4;                 // j in 0..3
    int wavesTotal = gridDim.x * (blockDim.x >> 6);
    for (int n = blockIdx.x * (blockDim.x >> 6) + wid; n < N; n += wavesTotal) {
        int start = (n == 0) ? 0 : off[n - 1];        // off[] holds END after scatter
        int end = off[n];
        float sum = 0.f;
        for (int e = start + j; e < end; e += 4)
            sum += g1[(size_t)csr_src[e] * HID + k];
        sum += __shfl_xor(sum, 16, 64);
        sum += __shfl_xor(sum, 32, 64);
        if (lane < 16) {
            float v = dinv[n] * (sum + g1[(size_t)n * HID + k]) + b1[k];
            h[(size_t)n * HID + k] = fmaxf(v, 0.f);
        }
    }
}

// g2[n][c] = (sum_k h[n][k] * W2[k][c]) * dinv[n]
__global__ void transform2_kernel(const float* __restrict__ h,
                                  const float* __restrict__ W2,
                                  const float* __restrict__ dinv,
                                  float* __restrict__ g2, int N) {
    int total = N * NC;
    for (int idx = blockIdx.x * blockDim.x + threadIdx.x; idx < total;
         idx += gridDim.x * blockDim.x) {
        int n = idx >> 3, c = idx & 7;
        float s = 0.f;
#pragma unroll
        for (int k = 0; k < HID; ++k) s += h[n * HID + k] * W2[k * NC + c];
        g2[idx] = s * dinv[n];
    }
}

// wave per node: 8 feature lanes x 8 edge-ways; fused log_softmax
__global__ void agg2_kernel(const int* __restrict__ off, const int* __restrict__ csr_src,
                            const float* __restrict__ g2, const float* __restrict__ dinv,
                            const float* __restrict__ b2, float* __restrict__ out, int N) {
    int wid = threadIdx.x >> 6;
    int lane = threadIdx.x & 63;
    int k = lane & 7, j = lane >> 3;                  // j in 0..7
    int wavesTotal = gridDim.x * (blockDim.x >> 6);
    for (int n = blockIdx.x * (blockDim.x >> 6) + wid; n < N; n += wavesTotal) {
        int start = (n == 0) ? 0 : off[n - 1];
        int end = off[n];
        float sum = 0.f;
        for (int e = start + j; e < end; e += 8)
            sum += g2[(size_t)csr_src[e] * NC + k];
        sum += __shfl_xor(sum, 8, 64);
        sum += __shfl_xor(sum, 16, 64);
        sum += __shfl_xor(sum, 32, 64);
        float logit = dinv[n] * (sum + g2[(size_t)n * NC + k]) + b2[k];
        float m = logit;
        m = fmaxf(m, __shfl_xor(m, 1, 64));
        m = fmaxf(m, __shfl_xor(m, 2, 64));
        m = fmaxf(m, __shfl_xor(m, 4, 64));
        float ex = __expf(logit - m);
        float s = ex;
        s += __shfl_xor(s, 1, 64);
        s += __shfl_xor(s, 2, 64);
        s += __shfl_xor(s, 4, 64);
        float lse = m + __logf(s);
        if (lane < 8) out[(size_t)n * NC + k] = logit - lse;
    }
}

extern "C" void kernel_launch(void* const* d_in, const int* in_sizes, int n_in,
                              void* d_out, int out_size, void* d_ws, size_t ws_size,
                              hipStream_t stream) {
    const float* x  = (const float*)d_in[0];
    const void*  ei = d_in[1];
    const float* W1 = (const float*)d_in[2];
    const float* b1 = (const float*)d_in[3];
    const float* W2 = (const float*)d_in[4];
    const float* b2 = (const float*)d_in[5];

    const int N = in_sizes[0] / FIN;
    const int E = in_sizes[1] / 2;
    const int NB = (N + 1023) / 1024;

    char* p = (char*)d_ws;
    int*   counts  = (int*)p;            p += (size_t)N * 4;
    int*   off     = (int*)p;            p += (size_t)N * 4;
    int*   bsum    = (int*)p;            p += (size_t)((NB + 63) & ~63) * 4;
    int*   csr_src = (int*)p;            p += (size_t)E * 4;
    float* dinv    = (float*)p;          p += (size_t)N * 4;
    float* g1      = (float*)p;          p += (size_t)N * HID * 4;
    float* h       = (float*)p;          p += (size_t)N * HID * 4;
    float* g2      = (float*)p;          p += (size_t)N * NC * 4;
    int*   flag    = (int*)p;

    hipMemsetAsync(counts, 0, (size_t)N * sizeof(int), stream);

    detect64_kernel<<<1, 64, 0, stream>>>(ei, E, N, flag);
    // 1024 blocks co-resident (4/CU) so blockIdx%8 -> XCD pinning holds
    hist_part_kernel<<<1024, 256, 0, stream>>>(ei, E, N, flag, counts);
    scanA_kernel<<<NB, 256, 0, stream>>>(counts, off, bsum, N);
    scanB_kernel<<<1, 64, 0, stream>>>(bsum, NB);
    scanC_kernel<<<(N + 255) / 256, 256, 0, stream>>>(off, bsum, N);
    dinv_kernel<<<(N + 255) / 256, 256, 0, stream>>>(counts, dinv, N);
    scatter_part_kernel<<<1024, 256, 0, stream>>>(ei, E, N, flag, off, csr_src);

    transform1_kernel<<<(N + 15) / 16, 256, 0, stream>>>(x, W1, dinv, g1, N);
    agg1_kernel<<<8192, 256, 0, stream>>>(off, csr_src, g1, dinv, b1, h, N);
    transform2_kernel<<<2048, 256, 0, stream>>>(h, W2, dinv, g2, N);
    agg2_kernel<<<8192, 256, 0, stream>>>(off, csr_src, g2, dinv, b2,
                                          (float*)d_out, N);
}